// Round 8
// baseline (459.657 us; speedup 1.0000x reference)
//
#include <hip/hip_runtime.h>
#include <hip/hip_cooperative_groups.h>

namespace cg = cooperative_groups;

#define F_EDGE 8
#define H 8

__device__ __forceinline__ unsigned short f2bf(float f) {
    unsigned u = __float_as_uint(f);
    unsigned r = u + 0x7fffu + ((u >> 16) & 1u);
    return (unsigned short)(r >> 16);
}
__device__ __forceinline__ float bflo(unsigned u) { return __uint_as_float(u << 16); }
__device__ __forceinline__ float bfhi(unsigned u) { return __uint_as_float(u & 0xffff0000u); }

// ---------------- phase bodies (shared by mega + discrete fallback) ---------

// Per-node precompute, grid-stride over 32-node units. Weights loaded to LDS
// ONCE per phase (identical across units).
//   Pt[n][j][k]   = sum_i feat[n][i] * We[k][i*H+j]   (stored bf16)
//   q[n][j]       = sum_i feat[n][i] * be[i*H+j]
//   aggseed[n][j] = b[j] + sum_i feat[n][i] * root[i*H+j]
template <int IN, bool RELU>
__device__ __forceinline__ void prep_phase(
    const float* __restrict__ feat, const float* __restrict__ We,
    const float* __restrict__ be, const float* __restrict__ root,
    const float* __restrict__ b, unsigned short* __restrict__ Pt,
    float* __restrict__ q, float* __restrict__ aggseed, int n_nodes,
    float* smem) {
    int tid = threadIdx.x;
    for (int t = tid; t < IN * H * 12; t += 256) {
        int r = t / 12, m = t - r * 12;   // r = i*H + j
        float v = 0.f;
        if (m < 8) v = We[m * (IN * H) + r];
        else if (m == 8) v = be[r];
        else if (m == 9) v = root[r];
        smem[t] = v;
    }
    __syncthreads();

    int U = (n_nodes + 31) >> 5;
    int j = tid & 7;
    for (int u = blockIdx.x; u < U; u += gridDim.x) {
        int n = u * 32 + (tid >> 3);
        if (n >= n_nodes) continue;

        float f[IN];
        const float4* fv = (const float4*)(feat + (long long)n * IN);
#pragma unroll
        for (int i4 = 0; i4 < IN / 4; ++i4) {
            float4 v = fv[i4];
            f[i4 * 4 + 0] = v.x; f[i4 * 4 + 1] = v.y;
            f[i4 * 4 + 2] = v.z; f[i4 * 4 + 3] = v.w;
        }
        if (RELU) {
#pragma unroll
            for (int i = 0; i < IN; ++i) f[i] = f[i] > 0.f ? f[i] : 0.f;
        }

        float p[8] = {0.f, 0.f, 0.f, 0.f, 0.f, 0.f, 0.f, 0.f};
        float qq = 0.f, hr = 0.f;
#pragma unroll
        for (int i = 0; i < IN; ++i) {
            const float* row = &smem[(i * 8 + j) * 12];
            float4 w0 = *(const float4*)row;
            float4 w1 = *(const float4*)(row + 4);
            float2 br = *(const float2*)(row + 8);
            float fi = f[i];
            p[0] = fmaf(fi, w0.x, p[0]); p[1] = fmaf(fi, w0.y, p[1]);
            p[2] = fmaf(fi, w0.z, p[2]); p[3] = fmaf(fi, w0.w, p[3]);
            p[4] = fmaf(fi, w1.x, p[4]); p[5] = fmaf(fi, w1.y, p[5]);
            p[6] = fmaf(fi, w1.z, p[6]); p[7] = fmaf(fi, w1.w, p[7]);
            qq = fmaf(fi, br.x, qq);
            hr = fmaf(fi, br.y, hr);
        }
        uint4 pw;
        pw.x = (unsigned)f2bf(p[0]) | ((unsigned)f2bf(p[1]) << 16);
        pw.y = (unsigned)f2bf(p[2]) | ((unsigned)f2bf(p[3]) << 16);
        pw.z = (unsigned)f2bf(p[4]) | ((unsigned)f2bf(p[5]) << 16);
        pw.w = (unsigned)f2bf(p[6]) | ((unsigned)f2bf(p[7]) << 16);
        *(uint4*)(Pt + ((long long)n * H + j) * F_EDGE) = pw;
        q[(long long)n * H + j] = qq;
        aggseed[(long long)n * H + j] = hr + b[j];
    }
}

// Flat edge pass (R0-proven structure): 8 lanes/edge, grid-stride.
//   msg_j = q[src][j] + sum_k ea[e][k] * Pt[src][j][k];  atomicAdd(agg[dst][j])
__device__ __forceinline__ void edge_phase(
    const int* __restrict__ ei, const float* __restrict__ ea,
    const unsigned short* __restrict__ Pt, const float* __restrict__ q,
    float* __restrict__ agg, int E) {
    long long total = (long long)E * 8;
    long long stride = (long long)gridDim.x * 256;
    for (long long gid = (long long)blockIdx.x * 256 + threadIdx.x;
         gid < total; gid += stride) {
        int e = (int)(gid >> 3);
        int j = (int)(gid & 7);

        int src = ei[e];
        int dst = ei[E + e];

        const float4* av = (const float4*)(ea + (long long)e * F_EDGE);
        float4 a0 = av[0], a1 = av[1];
        uint4 pw = *(const uint4*)(Pt + ((long long)src * H + j) * F_EDGE);
        float m = q[(long long)src * H + j];

        m = fmaf(a0.x, bflo(pw.x), m);
        m = fmaf(a0.y, bfhi(pw.x), m);
        m = fmaf(a0.z, bflo(pw.y), m);
        m = fmaf(a0.w, bfhi(pw.y), m);
        m = fmaf(a1.x, bflo(pw.z), m);
        m = fmaf(a1.y, bfhi(pw.z), m);
        m = fmaf(a1.z, bflo(pw.w), m);
        m = fmaf(a1.w, bfhi(pw.w), m);

        unsafeAtomicAdd(&agg[(long long)dst * H + j], m);
    }
}

// Pool: LDS bins per 1024-node chunk (batch sorted -> few hot bins), then one
// global atomic per nonzero bin. Grid-stride over chunks.
__device__ __forceinline__ void pool_phase(
    const float* __restrict__ h2pre, const int* __restrict__ batch,
    const float* __restrict__ Wlast, float* __restrict__ out,
    int n_nodes, int n_graphs, float* bins) {
    float wl[8];
#pragma unroll
    for (int j = 0; j < 8; ++j) wl[j] = Wlast[j];
    bool use_bins = (n_graphs <= 512);

    int U = (n_nodes + 1023) >> 10;
    for (int u = blockIdx.x; u < U; u += gridDim.x) {
        if (use_bins) {
            for (int t = threadIdx.x; t < n_graphs; t += 256) bins[t] = 0.f;
            __syncthreads();
        }
        int base = u * 1024;
#pragma unroll
        for (int r = 0; r < 4; ++r) {
            int n = base + r * 256 + threadIdx.x;
            if (n < n_nodes) {
                const float4* hv = (const float4*)(h2pre + (long long)n * H);
                float4 h0 = hv[0], h1 = hv[1];
                float c = 0.f;
                c = fmaf(fmaxf(h0.x, 0.f), wl[0], c);
                c = fmaf(fmaxf(h0.y, 0.f), wl[1], c);
                c = fmaf(fmaxf(h0.z, 0.f), wl[2], c);
                c = fmaf(fmaxf(h0.w, 0.f), wl[3], c);
                c = fmaf(fmaxf(h1.x, 0.f), wl[4], c);
                c = fmaf(fmaxf(h1.y, 0.f), wl[5], c);
                c = fmaf(fmaxf(h1.z, 0.f), wl[6], c);
                c = fmaf(fmaxf(h1.w, 0.f), wl[7], c);
                if (use_bins) atomicAdd(&bins[batch[n]], c);
                else unsafeAtomicAdd(&out[batch[n]], c);
            }
        }
        if (use_bins) {
            __syncthreads();
            for (int t = threadIdx.x; t < n_graphs; t += 256) {
                float v = bins[t];
                if (v != 0.f) unsafeAtomicAdd(&out[t], v);
            }
            __syncthreads();   // safe reuse of bins on next chunk
        }
    }
}

// ---------------- mega kernel: whole pipeline, one dispatch -----------------

struct MegaArgs {
    const float* x; const int* ei; const float* ea; const int* batch;
    const float* We1; const float* be1; const float* root1; const float* b1;
    const float* We2; const float* be2; const float* root2; const float* b2;
    const float* Wlast; const float* blast;
    float* out;
    unsigned short* Pt1; unsigned short* Pt2;
    float* q1; float* q2; float* h1; float* h2;
    int n_nodes; int E; int out_n;
};

__global__ __launch_bounds__(256, 4) void mega_kernel(MegaArgs a) {
    cg::grid_group grid = cg::this_grid();
    __shared__ float smem[16 * H * 12];   // 6 KB: prep weights / pool bins

    // phase 0: out init (block 0) + prep layer 1
    if (blockIdx.x == 0) {
        float bl = a.blast[0];
        for (int t = threadIdx.x; t < a.out_n; t += 256) a.out[t] = bl;
    }
    prep_phase<16, false>(a.x, a.We1, a.be1, a.root1, a.b1,
                          a.Pt1, a.q1, a.h1, a.n_nodes, smem);
    grid.sync();
    // phase 1: edge pass 1 (atomics on top of seed in h1)
    edge_phase(a.ei, a.ea, a.Pt1, a.q1, a.h1, a.E);
    grid.sync();
    // phase 2: prep layer 2 (ReLU on h1)
    prep_phase<H, true>(a.h1, a.We2, a.be2, a.root2, a.b2,
                        a.Pt2, a.q2, a.h2, a.n_nodes, smem);
    grid.sync();
    // phase 3: edge pass 2
    edge_phase(a.ei, a.ea, a.Pt2, a.q2, a.h2, a.E);
    grid.sync();
    // phase 4: fused ReLU -> Wlast -> per-graph pooling
    pool_phase(a.h2, a.batch, a.Wlast, a.out, a.n_nodes, a.out_n, smem);
}

// ---------------- discrete fallback kernels (if coop launch refused) -------

template <int IN, bool RELU, bool INIT>
__global__ __launch_bounds__(256) void prep_kernel(
    const float* feat, const float* We, const float* be, const float* root,
    const float* b, unsigned short* Pt, float* q, float* aggseed, int n_nodes,
    float* out, const float* blast, int out_n) {
    __shared__ float smem[IN * H * 12];
    if (INIT && blockIdx.x == 0) {
        float bl = blast[0];
        for (int t = threadIdx.x; t < out_n; t += 256) out[t] = bl;
    }
    prep_phase<IN, RELU>(feat, We, be, root, b, Pt, q, aggseed, n_nodes, smem);
}

__global__ __launch_bounds__(256) void edge_kernel(
    const int* ei, const float* ea, const unsigned short* Pt, const float* q,
    float* agg, int E) {
    edge_phase(ei, ea, Pt, q, agg, E);
}

__global__ __launch_bounds__(256) void pool_kernel(
    const float* h2pre, const int* batch, const float* Wlast, float* out,
    int n_nodes, int n_graphs) {
    __shared__ float bins[512];
    pool_phase(h2pre, batch, Wlast, out, n_nodes, n_graphs, bins);
}

extern "C" void kernel_launch(void* const* d_in, const int* in_sizes, int n_in,
                              void* d_out, int out_size, void* d_ws, size_t ws_size,
                              hipStream_t stream) {
    const float* x     = (const float*)d_in[0];
    const int*   ei    = (const int*)d_in[1];
    const float* ea    = (const float*)d_in[2];
    const int*   batch = (const int*)d_in[3];
    const float* We1   = (const float*)d_in[4];
    const float* be1   = (const float*)d_in[5];
    const float* root1 = (const float*)d_in[6];
    const float* b1    = (const float*)d_in[7];
    const float* We2   = (const float*)d_in[8];
    const float* be2   = (const float*)d_in[9];
    const float* root2 = (const float*)d_in[10];
    const float* b2    = (const float*)d_in[11];
    const float* Wlast = (const float*)d_in[12];
    const float* blast = (const float*)d_in[13];
    float* out = (float*)d_out;

    int F_IN_rt = 16;
    int n_nodes = in_sizes[0] / F_IN_rt;
    int E = in_sizes[1] / 2;

    char* w = (char*)d_ws;
    auto take = [&](size_t bytes) {
        char* p = w;
        w += (bytes + 15) & ~(size_t)15;
        return p;
    };
    unsigned short* Pt1 = (unsigned short*)take((size_t)n_nodes * H * F_EDGE * 2);
    unsigned short* Pt2 = (unsigned short*)take((size_t)n_nodes * H * F_EDGE * 2);
    float* q1 = (float*)take((size_t)n_nodes * H * 4);
    float* q2 = (float*)take((size_t)n_nodes * H * 4);
    float* h1 = (float*)take((size_t)n_nodes * H * 4);   // seed1 -> h1 in place
    float* h2 = (float*)take((size_t)n_nodes * H * 4);   // seed2 -> h2 in place

    MegaArgs ka;
    ka.x = x; ka.ei = ei; ka.ea = ea; ka.batch = batch;
    ka.We1 = We1; ka.be1 = be1; ka.root1 = root1; ka.b1 = b1;
    ka.We2 = We2; ka.be2 = be2; ka.root2 = root2; ka.b2 = b2;
    ka.Wlast = Wlast; ka.blast = blast; ka.out = out;
    ka.Pt1 = Pt1; ka.Pt2 = Pt2; ka.q1 = q1; ka.q2 = q2; ka.h1 = h1; ka.h2 = h2;
    ka.n_nodes = n_nodes; ka.E = E; ka.out_n = out_size;

    // co-resident grid size: occupancy * CU count (computed once per process)
    static int coop_grid = 0;
    static bool coop_ok = true;
    if (coop_grid == 0) {
        int bpc = 0;
        if (hipOccupancyMaxActiveBlocksPerMultiprocessor(&bpc, mega_kernel, 256, 0)
                != hipSuccess || bpc <= 0) { bpc = 0; coop_ok = false; }
        int ncu = 256;
        hipDeviceProp_t prop;
        int dev = 0;
        if (hipGetDevice(&dev) == hipSuccess &&
            hipGetDeviceProperties(&prop, dev) == hipSuccess &&
            prop.multiProcessorCount > 0)
            ncu = prop.multiProcessorCount;
        coop_grid = bpc * ncu;
        if (coop_grid <= 0) { coop_grid = 1; coop_ok = false; }
    }

    bool launched = false;
    if (coop_ok) {
        void* kp[] = { (void*)&ka };
        hipError_t err = hipLaunchCooperativeKernel(
            (const void*)mega_kernel, dim3(coop_grid), dim3(256), kp, 0, stream);
        launched = (err == hipSuccess);
        if (!launched) coop_ok = false;   // remember; use fallback from now on
    }

    if (!launched) {
        // discrete fallback (R0-proven sequence)
        int nblocks = (n_nodes + 31) / 32;
        prep_kernel<16, false, true><<<nblocks, 256, 0, stream>>>(
            x, We1, be1, root1, b1, Pt1, q1, h1, n_nodes, out, blast, out_size);
        long long lanes = (long long)E * 8;
        int eblks = (int)((lanes + 255) / 256);
        edge_kernel<<<eblks, 256, 0, stream>>>(ei, ea, Pt1, q1, h1, E);
        prep_kernel<H, true, false><<<nblocks, 256, 0, stream>>>(
            h1, We2, be2, root2, b2, Pt2, q2, h2, n_nodes, nullptr, nullptr, 0);
        edge_kernel<<<eblks, 256, 0, stream>>>(ei, ea, Pt2, q2, h2, E);
        int pblocks = (n_nodes + 1023) / 1024;
        pool_kernel<<<pblocks, 256, 0, stream>>>(h2, batch, Wlast, out,
                                                 n_nodes, out_size);
    }
}